// Round 14
// baseline (160.857 us; speedup 1.0000x reference)
//
#include <hip/hip_runtime.h>
#include <math.h>

#define T_DIM 1024
#define B_DIM 16
#define C_DIM 1024
#define H_DIM 16
#define K_TAPS 7
#define PAD_LEFT 3
#define OUT_DIM 1024
#define M_DIM (T_DIM * B_DIM)   // 16384
#define HK 112
#define HKP 128
#define KD 1024
#define HWS 1032                // hw row stride in ushorts (1024 + 8 pad)

typedef __attribute__((ext_vector_type(8))) short bf16x8;
typedef __attribute__((ext_vector_type(4))) float f32x4;

__device__ __forceinline__ ushort f2bf(float f) {
    union { float f; unsigned u; } v; v.f = f;
    unsigned u = v.u;
    u += 0x7fffu + ((u >> 16) & 1u);
    return (ushort)(u >> 16);
}
__device__ __forceinline__ float bf2f(ushort h) {
    union { unsigned u; float f; } v; v.u = ((unsigned)h) << 16;
    return v.f;
}

// ---------------------------------------------------------------------------
// Fused prep: blocks 0-8191 convert x -> bf16 (8 elems/thread);
// blocks 8192+ transpose W1/Wq/W2 (fp32 [K][N] -> bf16 [N][K], zero-pad Wq).
// ---------------------------------------------------------------------------
__global__ __launch_bounds__(256) void prep(const float* __restrict__ x,
                                            ushort* __restrict__ xb,
                                            const float* __restrict__ W1s,
                                            const float* __restrict__ Wqs,
                                            const float* __restrict__ W2s,
                                            ushort* __restrict__ W1t,
                                            ushort* __restrict__ Wqt,
                                            ushort* __restrict__ W2t) {
    __shared__ float tile[32][33];
    const int bx = blockIdx.x;
    if (bx < 8192) {
        int i = bx * 256 + threadIdx.x;
        const float4* p = (const float4*)x;
        float4 a = p[2 * i], b = p[2 * i + 1];
        uint4 o;
        o.x = (unsigned)f2bf(a.x) | ((unsigned)f2bf(a.y) << 16);
        o.y = (unsigned)f2bf(a.z) | ((unsigned)f2bf(a.w) << 16);
        o.z = (unsigned)f2bf(b.x) | ((unsigned)f2bf(b.y) << 16);
        o.w = (unsigned)f2bf(b.z) | ((unsigned)f2bf(b.w) << 16);
        ((uint4*)xb)[i] = o;
        return;
    }
    int tb  = bx - 8192;
    int nbx = tb % 68;
    int k0  = (tb / 68) * 32;
    const float* W; ushort* Wt; int N, Npad, nb;
    if (nbx < 32)      { W = W1s; Wt = W1t; N = 1024; Npad = 1024; nb = nbx; }
    else if (nbx < 36) { W = Wqs; Wt = Wqt; N = 112;  Npad = 128;  nb = nbx - 32; }
    else               { W = W2s; Wt = W2t; N = 1024; Npad = 1024; nb = nbx - 36; }
    int n0 = nb * 32;
    int tx = threadIdx.x & 31, ty = threadIdx.x >> 5;
#pragma unroll
    for (int j = 0; j < 4; ++j) {
        int k = k0 + ty * 4 + j;
        int n = n0 + tx;
        tile[ty * 4 + j][tx] = (n < N) ? W[(size_t)k * N + n] : 0.f;
    }
    __syncthreads();
#pragma unroll
    for (int j = 0; j < 4; ++j) {
        int n = n0 + ty * 4 + j;
        if (n < Npad)
            Wt[(size_t)n * KD + k0 + tx] = f2bf(tile[tx][ty * 4 + j]);
    }
}

// ---------------------------------------------------------------------------
// 256x256 bf16 MFMA GEMM, 8-phase schedule (R9/R11/R13-verified, ~46 us,
// 0 bank conflicts). LDS = 8 half-tile slots = 128 KiB.
// Swizzle: 16B slot' = slot^((row>>1)&3), pre-swizzled source + swizzled read.
// vmcnt: steady 6; tail j=7: p2=4, p4=0.
// ---------------------------------------------------------------------------
#define PHASE(P2KS, MH, READB, STAGE_STMT, VM_STMT)                           \
    {                                                                         \
        if (READB) {                                                          \
            _Pragma("unroll")                                                 \
            for (int n = 0; n < 4; ++n)                                       \
                b[n] = *(const bf16x8*)(Bbase + (P2KS)*8192 + bOff + n*512);  \
        }                                                                     \
        bf16x8 a_[4];                                                         \
        _Pragma("unroll")                                                     \
        for (int m = 0; m < 4; ++m)                                           \
            a_[m] = *(const bf16x8*)(Abase + (P2KS)*8192 + aOff +             \
                                     (MH)*2048 + m*512);                      \
        STAGE_STMT;                                                           \
        VM_STMT;                                                              \
        __builtin_amdgcn_s_barrier();                                         \
        asm volatile("s_waitcnt lgkmcnt(0)" ::: "memory");                    \
        __builtin_amdgcn_sched_barrier(0);                                    \
        __builtin_amdgcn_s_setprio(1);                                        \
        _Pragma("unroll")                                                     \
        for (int m = 0; m < 4; ++m)                                           \
            _Pragma("unroll")                                                 \
            for (int n = 0; n < 4; ++n)                                       \
                acc[(MH)*4 + m][n] = __builtin_amdgcn_mfma_f32_16x16x32_bf16( \
                    a_[m], b[n], acc[(MH)*4 + m][n], 0, 0, 0);                \
        __builtin_amdgcn_s_setprio(0);                                        \
        __builtin_amdgcn_s_barrier();                                         \
        __builtin_amdgcn_sched_barrier(0);                                    \
    }

template <bool OUT_BF16>
__global__ __launch_bounds__(512, 1) void gemm8p(
    const ushort* __restrict__ A, const ushort* __restrict__ Bt,
    const float* __restrict__ bias, void* __restrict__ Cp, int ldc) {
    __shared__ ushort Lds[8 * 8192];   // A slots 0-3, B slots 4-7

    const int tid  = threadIdx.x;
    const int lane = tid & 63;
    const int wid  = tid >> 6;
    const int wr = wid >> 2;
    const int wc = wid & 3;
    const int fr = lane & 15;
    const int fq = lane >> 4;

    const int orig = blockIdx.x;
    const int nid  = (orig & 7) * 32 + (orig >> 3);
    const int bm = (nid >> 2) * 256;
    const int bn = (nid & 3) * 256;

    const int srow = tid >> 2;
    const int scol = ((tid & 3) ^ ((tid >> 3) & 3)) * 8;
    const size_t sA = (size_t)(bm + srow) * KD + scol;
    const size_t sB = (size_t)(bn + srow) * KD + scol;
    const int sdst = wid * 64 * 8;

    const int slotSw = (fq ^ ((fr >> 1) & 3)) * 8;
    const int aOff = (wr * 128 + fr) * 32 + slotSw;
    const int bOff = (wc * 64 + fr) * 32 + slotSw;
    const ushort* Abase = &Lds[0];
    const ushort* Bbase = &Lds[4 * 8192];

    f32x4 acc[8][4];
#pragma unroll
    for (int m = 0; m < 8; ++m)
#pragma unroll
        for (int n = 0; n < 4; ++n) acc[m][n] = (f32x4){0.f, 0.f, 0.f, 0.f};

    auto stageA = [&](int slot, int koff) {
#pragma unroll
        for (int i = 0; i < 2; ++i)
            __builtin_amdgcn_global_load_lds(
                (const __attribute__((address_space(1))) void*)(A + sA + koff + (size_t)i * 128 * KD),
                (__attribute__((address_space(3))) void*)(&Lds[slot * 8192 + i * 4096 + sdst]),
                16, 0, 0);
    };
    auto stageB = [&](int slot, int koff) {
#pragma unroll
        for (int i = 0; i < 2; ++i)
            __builtin_amdgcn_global_load_lds(
                (const __attribute__((address_space(1))) void*)(Bt + sB + koff + (size_t)i * 128 * KD),
                (__attribute__((address_space(3))) void*)(&Lds[(4 + slot) * 8192 + i * 4096 + sdst]),
                16, 0, 0);
    };

    stageA(0, 0);   stageB(0, 0);
    stageA(1, 32);  stageB(1, 32);
    stageA(2, 64);  stageB(2, 64);
    stageA(3, 96);  stageB(3, 96);
    asm volatile("s_waitcnt vmcnt(12)" ::: "memory");
    __builtin_amdgcn_sched_barrier(0);
    __builtin_amdgcn_s_barrier();
    __builtin_amdgcn_sched_barrier(0);

#pragma unroll 1
    for (int j = 0; j < 8; ++j) {
        bf16x8 b[4];
        const int e = 2 * j;

        PHASE(0, 0, 1,
              { if (j >= 1) stageA(3, (e + 1) * 64 + 32); },
              { asm volatile("s_waitcnt vmcnt(6)" ::: "memory");
                __builtin_amdgcn_sched_barrier(0); })
        PHASE(0, 1, 0,
              { if (j >= 1) stageB(3, (e + 1) * 64 + 32); },
              (void)0; )
        PHASE(1, 0, 1,
              { if (j < 7) stageA(0, (e + 2) * 64); },
              { if (j == 7) { asm volatile("s_waitcnt vmcnt(4)" ::: "memory"); }
                else        { asm volatile("s_waitcnt vmcnt(6)" ::: "memory"); }
                __builtin_amdgcn_sched_barrier(0); })
        PHASE(1, 1, 0,
              { if (j < 7) stageB(0, (e + 2) * 64); },
              (void)0; )
        PHASE(2, 0, 1,
              { if (j < 7) stageA(1, (e + 2) * 64 + 32); },
              { if (j == 7) { asm volatile("s_waitcnt vmcnt(0)" ::: "memory"); }
                else        { asm volatile("s_waitcnt vmcnt(6)" ::: "memory"); }
                __builtin_amdgcn_sched_barrier(0); })
        PHASE(2, 1, 0,
              { if (j < 7) stageB(1, (e + 2) * 64 + 32); },
              (void)0; )
        PHASE(3, 0, 1,
              { if (j < 7) stageA(2, (e + 3) * 64); },
              { asm volatile("s_waitcnt vmcnt(6)" ::: "memory");
                __builtin_amdgcn_sched_barrier(0); })
        PHASE(3, 1, 0,
              { if (j < 7) stageB(2, (e + 3) * 64); },
              (void)0; )
    }

    // epilogue: C/D layout col=lane&15, row=(lane>>4)*4+r
#pragma unroll
    for (int n = 0; n < 4; ++n) {
        int col = bn + wc * 64 + n * 16 + fr;
        float bv = bias[col];
#pragma unroll
        for (int m = 0; m < 8; ++m) {
#pragma unroll
            for (int r = 0; r < 4; ++r) {
                int row = bm + wr * 128 + m * 16 + fq * 4 + r;
                float v = acc[m][n][r] + bv;
                if (OUT_BF16)
                    ((ushort*)Cp)[(size_t)row * ldc + col] = f2bf(v);
                else
                    ((float*)Cp)[(size_t)row * ldc + col] = v;
            }
        }
    }
}

// ---------------------------------------------------------------------------
// Fused q-GEMM + softmax + dynamic conv. Block = (b, 16 consecutive t).
// h window (22 rows, padded stride) staged in LDS; q = hw[3..18] @ Wqt^T + bq
// computed in-kernel via MFMA (wave w covers n-frags {2w, 2w+1}, frag 7
// masked); softmax over 7 taps in LDS; then the 7-tap conv.
// ---------------------------------------------------------------------------
__global__ __launch_bounds__(256) void dynconv3(const ushort* __restrict__ h,
                                                const ushort* __restrict__ Wqt,
                                                const float* __restrict__ bq,
                                                const float* __restrict__ cbias,
                                                ushort* __restrict__ out) {
    __shared__ ushort hw[22 * HWS];   // 45.4 KB, padded rows (2064 B stride)
    __shared__ float qs[16][HK];      // 7 KB
    const int tid  = threadIdx.x;
    const int lane = tid & 63;
    const int wid  = tid >> 6;
    const int fr = lane & 15;
    const int fq = lane >> 4;
    const int b  = blockIdx.x & 15;
    const int t0 = (blockIdx.x >> 4) << 4;

    // stage h rows t0-3 .. t0+18 (zero OOB)
    for (int i = tid; i < 22 * 128; i += 256) {
        int wrow = i >> 7;
        int c8   = (i & 127) * 8;
        int tt   = t0 + wrow - PAD_LEFT;
        uint4 v = make_uint4(0, 0, 0, 0);
        if (tt >= 0 && tt < T_DIM)
            v = *(const uint4*)&h[((size_t)tt * B_DIM + b) * C_DIM + c8];
        *(uint4*)&hw[wrow * HWS + c8] = v;
    }
    __syncthreads();

    // q[tl][n] = sum_k h[t0+tl][k] * Wq[k][n] + bq[n], via 16x16x32 MFMA.
    // Mirrors the verified gemm operand mapping: a row = fr (h t-row),
    // b row = nf*16+fr (Wqt), out row = fq*4+r, col = nf*16+fr.
    {
        f32x4 acc0 = (f32x4){0.f, 0.f, 0.f, 0.f};
        f32x4 acc1 = (f32x4){0.f, 0.f, 0.f, 0.f};
        const int nf0 = wid * 2;
        const int nf1 = wid * 2 + 1;          // ==7 for wave 3: masked
        const ushort* aP  = &hw[(3 + fr) * HWS + fq * 8];
        const ushort* b0P = &Wqt[(size_t)(nf0 * 16 + fr) * KD + fq * 8];
        const ushort* b1P = &Wqt[(size_t)((nf1 < 7 ? nf1 : nf0) * 16 + fr) * KD + fq * 8];
#pragma unroll 4
        for (int k0 = 0; k0 < KD; k0 += 32) {
            bf16x8 a  = *(const bf16x8*)(aP + k0);
            bf16x8 v0 = *(const bf16x8*)(b0P + k0);
            bf16x8 v1 = *(const bf16x8*)(b1P + k0);
            acc0 = __builtin_amdgcn_mfma_f32_16x16x32_bf16(a, v0, acc0, 0, 0, 0);
            acc1 = __builtin_amdgcn_mfma_f32_16x16x32_bf16(a, v1, acc1, 0, 0, 0);
        }
        float bv0 = bq[nf0 * 16 + fr];
        float bv1 = (nf1 < 7) ? bq[nf1 * 16 + fr] : 0.f;
#pragma unroll
        for (int r = 0; r < 4; ++r) {
            int row = fq * 4 + r;
            qs[row][nf0 * 16 + fr] = acc0[r] + bv0;
            if (nf1 < 7) qs[row][nf1 * 16 + fr] = acc1[r] + bv1;
        }
    }
    __syncthreads();

    // softmax over the 7 taps, in place
    {
        int tl = tid >> 4, hh = tid & 15;
        float* p = &qs[tl][hh * K_TAPS];
        float mx = p[0];
#pragma unroll
        for (int k = 1; k < K_TAPS; ++k) mx = fmaxf(mx, p[k]);
        float e[K_TAPS], s = 0.f;
#pragma unroll
        for (int k = 0; k < K_TAPS; ++k) { e[k] = __expf(p[k] - mx); s += e[k]; }
        float inv = 1.f / s;
#pragma unroll
        for (int k = 0; k < K_TAPS; ++k) p[k] = e[k] * inv;
    }
    __syncthreads();

    // conv
    const int c  = tid * 4;
    const int hh = c >> 6;
    float4 bias = *(const float4*)&cbias[c];

    for (int tl = 0; tl < 16; ++tl) {
        float a0 = bias.x, a1 = bias.y, a2 = bias.z, a3 = bias.w;
#pragma unroll
        for (int k = 0; k < K_TAPS; ++k) {
            ushort4 hv = *(const ushort4*)&hw[(tl + k) * HWS + c];
            float wk = qs[tl][hh * K_TAPS + k];
            a0 = fmaf(bf2f(hv.x), wk, a0);
            a1 = fmaf(bf2f(hv.y), wk, a1);
            a2 = fmaf(bf2f(hv.z), wk, a2);
            a3 = fmaf(bf2f(hv.w), wk, a3);
        }
        ushort4 o;
        o.x = f2bf(a0); o.y = f2bf(a1); o.z = f2bf(a2); o.w = f2bf(a3);
        *(ushort4*)&out[((size_t)(t0 + tl) * B_DIM + b) * C_DIM + c] = o;
    }
}

// ---------------------------------------------------------------------------
extern "C" void kernel_launch(void* const* d_in, const int* in_sizes, int n_in,
                              void* d_out, int out_size, void* d_ws,
                              size_t ws_size, hipStream_t stream) {
    const float* x     = (const float*)d_in[0];
    const float* W1    = (const float*)d_in[1];
    const float* b1    = (const float*)d_in[2];
    const float* Wq    = (const float*)d_in[3];
    const float* bq    = (const float*)d_in[4];
    const float* cbias = (const float*)d_in[5];
    const float* W2    = (const float*)d_in[6];
    const float* b2    = (const float*)d_in[7];
    float* out = (float*)d_out;

    ushort* xb    = (ushort*)d_ws;
    ushort* hb    = xb    + (size_t)M_DIM * C_DIM;
    ushort* convb = hb    + (size_t)M_DIM * C_DIM;
    ushort* W1t   = convb + (size_t)M_DIM * C_DIM;
    ushort* W2t   = W1t   + (size_t)C_DIM * C_DIM;
    ushort* Wqt   = W2t   + (size_t)C_DIM * OUT_DIM;

    // 0) prep: x -> bf16, weights -> transposed bf16 (one launch)
    prep<<<dim3(8192 + 68 * 32), dim3(256), 0, stream>>>(
        x, xb, W1, Wq, W2, W1t, Wqt, W2t);

    // 1) h = bf16(x @ W1 + b1)
    gemm8p<true><<<dim3(256), dim3(512), 0, stream>>>(xb, W1t, b1, hb, C_DIM);

    // 2+3+4) q-GEMM + softmax + conv fused
    dynconv3<<<dim3(B_DIM * T_DIM / 16), dim3(256), 0, stream>>>(
        hb, Wqt, bq, cbias, convb);

    // 5) out = conv @ W2 + b2
    gemm8p<false><<<dim3(256), dim3(512), 0, stream>>>(convb, W2t, b2, out,
                                                       OUT_DIM);
}

// Round 15
// 148.148 us; speedup vs baseline: 1.0858x; 1.0858x over previous
//
#include <hip/hip_runtime.h>
#include <math.h>

#define T_DIM 1024
#define B_DIM 16
#define C_DIM 1024
#define H_DIM 16
#define K_TAPS 7
#define PAD_LEFT 3
#define OUT_DIM 1024
#define M_DIM (T_DIM * B_DIM)   // 16384
#define HK 112
#define HKP 128
#define KD 1024

typedef __attribute__((ext_vector_type(8))) short bf16x8;
typedef __attribute__((ext_vector_type(4))) float f32x4;

__device__ __forceinline__ ushort f2bf(float f) {
    union { float f; unsigned u; } v; v.f = f;
    unsigned u = v.u;
    u += 0x7fffu + ((u >> 16) & 1u);
    return (ushort)(u >> 16);
}
__device__ __forceinline__ float bf2f(ushort h) {
    union { unsigned u; float f; } v; v.u = ((unsigned)h) << 16;
    return v.f;
}

// ---------------------------------------------------------------------------
// Fused prep: blocks 0-8191 convert x -> bf16 (8 elems/thread);
// blocks 8192+ transpose W1/Wq/W2 (fp32 [K][N] -> bf16 [N][K], zero-pad Wq).
// ---------------------------------------------------------------------------
__global__ __launch_bounds__(256) void prep(const float* __restrict__ x,
                                            ushort* __restrict__ xb,
                                            const float* __restrict__ W1s,
                                            const float* __restrict__ Wqs,
                                            const float* __restrict__ W2s,
                                            ushort* __restrict__ W1t,
                                            ushort* __restrict__ Wqt,
                                            ushort* __restrict__ W2t) {
    __shared__ float tile[32][33];
    const int bx = blockIdx.x;
    if (bx < 8192) {
        int i = bx * 256 + threadIdx.x;
        const float4* p = (const float4*)x;
        float4 a = p[2 * i], b = p[2 * i + 1];
        uint4 o;
        o.x = (unsigned)f2bf(a.x) | ((unsigned)f2bf(a.y) << 16);
        o.y = (unsigned)f2bf(a.z) | ((unsigned)f2bf(a.w) << 16);
        o.z = (unsigned)f2bf(b.x) | ((unsigned)f2bf(b.y) << 16);
        o.w = (unsigned)f2bf(b.z) | ((unsigned)f2bf(b.w) << 16);
        ((uint4*)xb)[i] = o;
        return;
    }
    int tb  = bx - 8192;
    int nbx = tb % 68;
    int k0  = (tb / 68) * 32;
    const float* W; ushort* Wt; int N, Npad, nb;
    if (nbx < 32)      { W = W1s; Wt = W1t; N = 1024; Npad = 1024; nb = nbx; }
    else if (nbx < 36) { W = Wqs; Wt = Wqt; N = 112;  Npad = 128;  nb = nbx - 32; }
    else               { W = W2s; Wt = W2t; N = 1024; Npad = 1024; nb = nbx - 36; }
    int n0 = nb * 32;
    int tx = threadIdx.x & 31, ty = threadIdx.x >> 5;
#pragma unroll
    for (int j = 0; j < 4; ++j) {
        int k = k0 + ty * 4 + j;
        int n = n0 + tx;
        tile[ty * 4 + j][tx] = (n < N) ? W[(size_t)k * N + n] : 0.f;
    }
    __syncthreads();
#pragma unroll
    for (int j = 0; j < 4; ++j) {
        int n = n0 + ty * 4 + j;
        if (n < Npad)
            Wt[(size_t)n * KD + k0 + tx] = f2bf(tile[tx][ty * 4 + j]);
    }
}

// ---------------------------------------------------------------------------
// 256x256 bf16 MFMA GEMM, 8-phase schedule (R9/R11/R13-verified, ~46 us,
// 0 bank conflicts). LDS = 8 half-tile slots = 128 KiB.
// Swizzle: 16B slot' = slot^((row>>1)&3), pre-swizzled source + swizzled read.
// vmcnt ledger (re-derived R14): steady vmcnt(6) at p0 and p4 ONLY suffices
// (p2/p6 reads are 7th+-newest in the queue at the preceding wait); tail j=7
// keeps vmcnt(4)@p2 and vmcnt(0)@p4.
// ---------------------------------------------------------------------------
#define PHASE(P2KS, MH, READB, STAGE_STMT, VM_STMT)                           \
    {                                                                         \
        if (READB) {                                                          \
            _Pragma("unroll")                                                 \
            for (int n = 0; n < 4; ++n)                                       \
                b[n] = *(const bf16x8*)(Bbase + (P2KS)*8192 + bOff + n*512);  \
        }                                                                     \
        bf16x8 a_[4];                                                         \
        _Pragma("unroll")                                                     \
        for (int m = 0; m < 4; ++m)                                           \
            a_[m] = *(const bf16x8*)(Abase + (P2KS)*8192 + aOff +             \
                                     (MH)*2048 + m*512);                      \
        STAGE_STMT;                                                           \
        VM_STMT;                                                              \
        __builtin_amdgcn_s_barrier();                                         \
        asm volatile("s_waitcnt lgkmcnt(0)" ::: "memory");                    \
        __builtin_amdgcn_sched_barrier(0);                                    \
        __builtin_amdgcn_s_setprio(1);                                        \
        _Pragma("unroll")                                                     \
        for (int m = 0; m < 4; ++m)                                           \
            _Pragma("unroll")                                                 \
            for (int n = 0; n < 4; ++n)                                       \
                acc[(MH)*4 + m][n] = __builtin_amdgcn_mfma_f32_16x16x32_bf16( \
                    a_[m], b[n], acc[(MH)*4 + m][n], 0, 0, 0);                \
        __builtin_amdgcn_s_setprio(0);                                        \
        __builtin_amdgcn_s_barrier();                                         \
        __builtin_amdgcn_sched_barrier(0);                                    \
    }

template <bool OUT_BF16>
__global__ __launch_bounds__(512, 1) void gemm8p(
    const ushort* __restrict__ A, const ushort* __restrict__ Bt,
    const float* __restrict__ bias, void* __restrict__ Cp, int ldc) {
    __shared__ ushort Lds[8 * 8192];   // A slots 0-3, B slots 4-7

    const int tid  = threadIdx.x;
    const int lane = tid & 63;
    const int wid  = tid >> 6;
    const int wr = wid >> 2;
    const int wc = wid & 3;
    const int fr = lane & 15;
    const int fq = lane >> 4;

    const int orig = blockIdx.x;
    const int nid  = (orig & 7) * 32 + (orig >> 3);
    const int bm = (nid >> 2) * 256;
    const int bn = (nid & 3) * 256;

    const int srow = tid >> 2;
    const int scol = ((tid & 3) ^ ((tid >> 3) & 3)) * 8;
    const size_t sA = (size_t)(bm + srow) * KD + scol;
    const size_t sB = (size_t)(bn + srow) * KD + scol;
    const int sdst = wid * 64 * 8;

    const int slotSw = (fq ^ ((fr >> 1) & 3)) * 8;
    const int aOff = (wr * 128 + fr) * 32 + slotSw;
    const int bOff = (wc * 64 + fr) * 32 + slotSw;
    const ushort* Abase = &Lds[0];
    const ushort* Bbase = &Lds[4 * 8192];

    f32x4 acc[8][4];
#pragma unroll
    for (int m = 0; m < 8; ++m)
#pragma unroll
        for (int n = 0; n < 4; ++n) acc[m][n] = (f32x4){0.f, 0.f, 0.f, 0.f};

    auto stageA = [&](int slot, int koff) {
#pragma unroll
        for (int i = 0; i < 2; ++i)
            __builtin_amdgcn_global_load_lds(
                (const __attribute__((address_space(1))) void*)(A + sA + koff + (size_t)i * 128 * KD),
                (__attribute__((address_space(3))) void*)(&Lds[slot * 8192 + i * 4096 + sdst]),
                16, 0, 0);
    };
    auto stageB = [&](int slot, int koff) {
#pragma unroll
        for (int i = 0; i < 2; ++i)
            __builtin_amdgcn_global_load_lds(
                (const __attribute__((address_space(1))) void*)(Bt + sB + koff + (size_t)i * 128 * KD),
                (__attribute__((address_space(3))) void*)(&Lds[(4 + slot) * 8192 + i * 4096 + sdst]),
                16, 0, 0);
    };

    stageA(0, 0);   stageB(0, 0);
    stageA(1, 32);  stageB(1, 32);
    stageA(2, 64);  stageB(2, 64);
    stageA(3, 96);  stageB(3, 96);
    asm volatile("s_waitcnt vmcnt(12)" ::: "memory");
    __builtin_amdgcn_sched_barrier(0);
    __builtin_amdgcn_s_barrier();
    __builtin_amdgcn_sched_barrier(0);

#pragma unroll 1
    for (int j = 0; j < 8; ++j) {
        bf16x8 b[4];
        const int e = 2 * j;

        PHASE(0, 0, 1,
              { if (j >= 1) stageA(3, (e + 1) * 64 + 32); },
              { asm volatile("s_waitcnt vmcnt(6)" ::: "memory");
                __builtin_amdgcn_sched_barrier(0); })
        PHASE(0, 1, 0,
              { if (j >= 1) stageB(3, (e + 1) * 64 + 32); },
              (void)0; )
        PHASE(1, 0, 1,
              { if (j < 7) stageA(0, (e + 2) * 64); },
              { if (j == 7) { asm volatile("s_waitcnt vmcnt(4)" ::: "memory");
                              __builtin_amdgcn_sched_barrier(0); } })
        PHASE(1, 1, 0,
              { if (j < 7) stageB(0, (e + 2) * 64); },
              (void)0; )
        PHASE(2, 0, 1,
              { if (j < 7) stageA(1, (e + 2) * 64 + 32); },
              { if (j == 7) { asm volatile("s_waitcnt vmcnt(0)" ::: "memory"); }
                else        { asm volatile("s_waitcnt vmcnt(6)" ::: "memory"); }
                __builtin_amdgcn_sched_barrier(0); })
        PHASE(2, 1, 0,
              { if (j < 7) stageB(1, (e + 2) * 64 + 32); },
              (void)0; )
        PHASE(3, 0, 1,
              { if (j < 7) stageA(2, (e + 3) * 64); },
              (void)0; )
        PHASE(3, 1, 0,
              { if (j < 7) stageB(2, (e + 3) * 64); },
              (void)0; )
    }

    // epilogue: C/D layout col=lane&15, row=(lane>>4)*4+r
#pragma unroll
    for (int n = 0; n < 4; ++n) {
        int col = bn + wc * 64 + n * 16 + fr;
        float bv = bias[col];
#pragma unroll
        for (int m = 0; m < 8; ++m) {
#pragma unroll
            for (int r = 0; r < 4; ++r) {
                int row = bm + wr * 128 + m * 16 + fq * 4 + r;
                float v = acc[m][n][r] + bv;
                if (OUT_BF16)
                    ((ushort*)Cp)[(size_t)row * ldc + col] = f2bf(v);
                else
                    ((float*)Cp)[(size_t)row * ldc + col] = v;
            }
        }
    }
}

// ---------------------------------------------------------------------------
// Skinny GEMM for q: BM=64, BN=128(pad of 112), BK=32, 256 thr.
// ---------------------------------------------------------------------------
__global__ __launch_bounds__(256) void gemm_small(const ushort* __restrict__ A,
                                                  const ushort* __restrict__ Bt,
                                                  const float* __restrict__ bias,
                                                  float* __restrict__ Cp) {
    __shared__ ushort Als[64 * 32];
    __shared__ ushort Bls[128 * 32];
    const int tid  = threadIdx.x;
    const int lane = tid & 63;
    const int wid  = tid >> 6;
    const int wr = wid >> 1, wc = wid & 1;
    const int bm = blockIdx.y * 64;
    const int fq = lane >> 4, fr = lane & 15;

    f32x4 acc[2][4];
#pragma unroll
    for (int m = 0; m < 2; ++m)
#pragma unroll
        for (int n = 0; n < 4; ++n) acc[m][n] = (f32x4){0.f, 0.f, 0.f, 0.f};

    const int rA = tid >> 2, oA = (tid & 3) * 8;
    for (int k0 = 0; k0 < KD; k0 += 32) {
        __builtin_amdgcn_global_load_lds(
            (const __attribute__((address_space(1))) void*)&A[(size_t)(bm + rA) * KD + k0 + oA],
            (__attribute__((address_space(3))) void*)&Als[wid * 64 * 8], 16, 0, 0);
#pragma unroll
        for (int i = 0; i < 2; ++i) {
            int c = i * 256 + tid;
            __builtin_amdgcn_global_load_lds(
                (const __attribute__((address_space(1))) void*)&Bt[(size_t)(c >> 2) * KD + k0 + (c & 3) * 8],
                (__attribute__((address_space(3))) void*)&Bls[(i * 256 + wid * 64) * 8], 16, 0, 0);
        }
        __syncthreads();

        bf16x8 af[2], bfr[4];
#pragma unroll
        for (int m = 0; m < 2; ++m)
            af[m] = *(const bf16x8*)&Als[(wr * 32 + m * 16 + fr) * 32 + fq * 8];
#pragma unroll
        for (int n = 0; n < 4; ++n)
            bfr[n] = *(const bf16x8*)&Bls[(wc * 64 + n * 16 + fr) * 32 + fq * 8];
#pragma unroll
        for (int m = 0; m < 2; ++m)
#pragma unroll
            for (int n = 0; n < 4; ++n)
                acc[m][n] = __builtin_amdgcn_mfma_f32_16x16x32_bf16(
                    af[m], bfr[n], acc[m][n], 0, 0, 0);
        __syncthreads();
    }

#pragma unroll
    for (int m = 0; m < 2; ++m) {
#pragma unroll
        for (int n = 0; n < 4; ++n) {
            int col = wc * 64 + n * 16 + fr;
            if (col >= HK) continue;
            float bv = bias[col];
#pragma unroll
            for (int r = 0; r < 4; ++r) {
                int row = bm + wr * 32 + m * 16 + fq * 4 + r;
                Cp[(size_t)row * HK + col] = acc[m][n][r] + bv;
            }
        }
    }
}

// ---------------------------------------------------------------------------
// Tiled dynamic conv + fused softmax: block = (b, 16 consecutive t).
// ---------------------------------------------------------------------------
__global__ __launch_bounds__(256) void dynconv2(const ushort* __restrict__ h,
                                                const float* __restrict__ q,
                                                const float* __restrict__ cbias,
                                                ushort* __restrict__ out) {
    __shared__ ushort hw[22][1024];
    __shared__ float wsm[16][HK];
    const int tid = threadIdx.x;
    const int b  = blockIdx.x & 15;
    const int t0 = (blockIdx.x >> 4) << 4;

    for (int i = tid; i < 22 * 128; i += 256) {
        int wrow = i >> 7;
        int c8   = (i & 127) * 8;
        int tt   = t0 + wrow - PAD_LEFT;
        uint4 v = make_uint4(0, 0, 0, 0);
        if (tt >= 0 && tt < T_DIM)
            v = *(const uint4*)&h[((size_t)tt * B_DIM + b) * C_DIM + c8];
        *(uint4*)&hw[wrow][c8] = v;
    }
    {
        int tl = tid >> 4, hh = tid & 15;
        int m = (t0 + tl) * B_DIM + b;
        const float* p = &q[(size_t)m * HK + hh * K_TAPS];
        float mx = p[0];
#pragma unroll
        for (int k = 1; k < K_TAPS; ++k) mx = fmaxf(mx, p[k]);
        float e[K_TAPS], s = 0.f;
#pragma unroll
        for (int k = 0; k < K_TAPS; ++k) { e[k] = __expf(p[k] - mx); s += e[k]; }
        float inv = 1.f / s;
#pragma unroll
        for (int k = 0; k < K_TAPS; ++k) wsm[tl][hh * K_TAPS + k] = e[k] * inv;
    }
    __syncthreads();

    const int c  = tid * 4;
    const int hh = c >> 6;
    float4 bias = *(const float4*)&cbias[c];

    for (int tl = 0; tl < 16; ++tl) {
        float a0 = bias.x, a1 = bias.y, a2 = bias.z, a3 = bias.w;
#pragma unroll
        for (int k = 0; k < K_TAPS; ++k) {
            ushort4 hv = *(const ushort4*)&hw[tl + k][c];
            float wk = wsm[tl][hh * K_TAPS + k];
            a0 = fmaf(bf2f(hv.x), wk, a0);
            a1 = fmaf(bf2f(hv.y), wk, a1);
            a2 = fmaf(bf2f(hv.z), wk, a2);
            a3 = fmaf(bf2f(hv.w), wk, a3);
        }
        ushort4 o;
        o.x = f2bf(a0); o.y = f2bf(a1); o.z = f2bf(a2); o.w = f2bf(a3);
        *(ushort4*)&out[((size_t)(t0 + tl) * B_DIM + b) * C_DIM + c] = o;
    }
}

// ---------------------------------------------------------------------------
extern "C" void kernel_launch(void* const* d_in, const int* in_sizes, int n_in,
                              void* d_out, int out_size, void* d_ws,
                              size_t ws_size, hipStream_t stream) {
    const float* x     = (const float*)d_in[0];
    const float* W1    = (const float*)d_in[1];
    const float* b1    = (const float*)d_in[2];
    const float* Wq    = (const float*)d_in[3];
    const float* bq    = (const float*)d_in[4];
    const float* cbias = (const float*)d_in[5];
    const float* W2    = (const float*)d_in[6];
    const float* b2    = (const float*)d_in[7];
    float* out = (float*)d_out;

    ushort* xb    = (ushort*)d_ws;
    ushort* hb    = xb    + (size_t)M_DIM * C_DIM;
    ushort* convb = hb    + (size_t)M_DIM * C_DIM;
    ushort* W1t   = convb + (size_t)M_DIM * C_DIM;
    ushort* W2t   = W1t   + (size_t)C_DIM * C_DIM;
    ushort* Wqt   = W2t   + (size_t)C_DIM * OUT_DIM;
    float*  q     = (float*)(Wqt + (size_t)HKP * C_DIM);

    // 0) prep: x -> bf16, weights -> transposed bf16 (one launch)
    prep<<<dim3(8192 + 68 * 32), dim3(256), 0, stream>>>(
        x, xb, W1, Wq, W2, W1t, Wqt, W2t);

    // 1) h = bf16(x @ W1 + b1)
    gemm8p<true><<<dim3(256), dim3(512), 0, stream>>>(xb, W1t, b1, hb, C_DIM);

    // 2) q = h @ Wq + bq   [16384 x 112]
    gemm_small<<<dim3(1, M_DIM / 64), dim3(256), 0, stream>>>(hb, Wqt, bq, q);

    // 3+4) conv = bf16(dynconv(h, softmax(q)) + conv_bias)
    dynconv2<<<dim3(B_DIM * T_DIM / 16), dim3(256), 0, stream>>>(
        hb, q, cbias, convb);

    // 5) out = conv @ W2 + b2
    gemm8p<false><<<dim3(256), dim3(512), 0, stream>>>(convb, W2t, b2, out,
                                                       OUT_DIM);
}

// Round 16
// 147.301 us; speedup vs baseline: 1.0920x; 1.0057x over previous
//
#include <hip/hip_runtime.h>
#include <math.h>

#define T_DIM 1024
#define B_DIM 16
#define C_DIM 1024
#define H_DIM 16
#define K_TAPS 7
#define PAD_LEFT 3
#define OUT_DIM 1024
#define M_DIM (T_DIM * B_DIM)   // 16384
#define HK 112
#define HKP 128
#define KD 1024

typedef __attribute__((ext_vector_type(8))) short bf16x8;
typedef __attribute__((ext_vector_type(4))) float f32x4;

__device__ __forceinline__ ushort f2bf(float f) {
    union { float f; unsigned u; } v; v.f = f;
    unsigned u = v.u;
    u += 0x7fffu + ((u >> 16) & 1u);
    return (ushort)(u >> 16);
}
__device__ __forceinline__ float bf2f(ushort h) {
    union { unsigned u; float f; } v; v.u = ((unsigned)h) << 16;
    return v.f;
}

// ---------------------------------------------------------------------------
// Fused prep: blocks 0-8191 convert x -> bf16; blocks 8192+ transpose weights.
// ---------------------------------------------------------------------------
__global__ __launch_bounds__(256) void prep(const float* __restrict__ x,
                                            ushort* __restrict__ xb,
                                            const float* __restrict__ W1s,
                                            const float* __restrict__ Wqs,
                                            const float* __restrict__ W2s,
                                            ushort* __restrict__ W1t,
                                            ushort* __restrict__ Wqt,
                                            ushort* __restrict__ W2t) {
    __shared__ float tile[32][33];
    const int bx = blockIdx.x;
    if (bx < 8192) {
        int i = bx * 256 + threadIdx.x;
        const float4* p = (const float4*)x;
        float4 a = p[2 * i], b = p[2 * i + 1];
        uint4 o;
        o.x = (unsigned)f2bf(a.x) | ((unsigned)f2bf(a.y) << 16);
        o.y = (unsigned)f2bf(a.z) | ((unsigned)f2bf(a.w) << 16);
        o.z = (unsigned)f2bf(b.x) | ((unsigned)f2bf(b.y) << 16);
        o.w = (unsigned)f2bf(b.z) | ((unsigned)f2bf(b.w) << 16);
        ((uint4*)xb)[i] = o;
        return;
    }
    int tb  = bx - 8192;
    int nbx = tb % 68;
    int k0  = (tb / 68) * 32;
    const float* W; ushort* Wt; int N, Npad, nb;
    if (nbx < 32)      { W = W1s; Wt = W1t; N = 1024; Npad = 1024; nb = nbx; }
    else if (nbx < 36) { W = Wqs; Wt = Wqt; N = 112;  Npad = 128;  nb = nbx - 32; }
    else               { W = W2s; Wt = W2t; N = 1024; Npad = 1024; nb = nbx - 36; }
    int n0 = nb * 32;
    int tx = threadIdx.x & 31, ty = threadIdx.x >> 5;
#pragma unroll
    for (int j = 0; j < 4; ++j) {
        int k = k0 + ty * 4 + j;
        int n = n0 + tx;
        tile[ty * 4 + j][tx] = (n < N) ? W[(size_t)k * N + n] : 0.f;
    }
    __syncthreads();
#pragma unroll
    for (int j = 0; j < 4; ++j) {
        int n = n0 + ty * 4 + j;
        if (n < Npad)
            Wt[(size_t)n * KD + k0 + tx] = f2bf(tile[tx][ty * 4 + j]);
    }
}

// ---------------------------------------------------------------------------
// 256x256 bf16 MFMA GEMM, 4 MEGA-phase schedule (merged from the verified
// 8-phase R9/R13 kernel): per mega-phase {12 ds_read_b128 || stage A+B
// slot-pair -> vmcnt(8) -> barrier -> lgkm0 -> 32 MFMA -> barrier}.
// Halves barrier/sync count vs R15. Slot rotation, swizzle, and C-layout
// byte-identical to the verified kernel. vmcnt ledger (induction-checked):
// steady vmcnt(8); tail j=7: mp1=vmcnt(4), mp2=vmcnt(0), mp3 none.
// ---------------------------------------------------------------------------
#define MPHASE(SLOT, STAGE_STMT, VM_STMT)                                     \
    {                                                                         \
        bf16x8 b[4], a_[8];                                                   \
        _Pragma("unroll")                                                     \
        for (int n = 0; n < 4; ++n)                                           \
            b[n] = *(const bf16x8*)(Bbase + (SLOT)*8192 + bOff + n*512);      \
        _Pragma("unroll")                                                     \
        for (int m = 0; m < 8; ++m)                                           \
            a_[m] = *(const bf16x8*)(Abase + (SLOT)*8192 + aOff +             \
                                     (m >> 2)*2048 + (m & 3)*512);            \
        STAGE_STMT;                                                           \
        VM_STMT;                                                              \
        __builtin_amdgcn_s_barrier();                                         \
        asm volatile("s_waitcnt lgkmcnt(0)" ::: "memory");                    \
        __builtin_amdgcn_sched_barrier(0);                                    \
        __builtin_amdgcn_s_setprio(1);                                        \
        _Pragma("unroll")                                                     \
        for (int m = 0; m < 8; ++m)                                           \
            _Pragma("unroll")                                                 \
            for (int n = 0; n < 4; ++n)                                       \
                acc[m][n] = __builtin_amdgcn_mfma_f32_16x16x32_bf16(          \
                    a_[m], b[n], acc[m][n], 0, 0, 0);                         \
        __builtin_amdgcn_s_setprio(0);                                        \
        __builtin_amdgcn_s_barrier();                                         \
        __builtin_amdgcn_sched_barrier(0);                                    \
    }

template <bool OUT_BF16>
__global__ __launch_bounds__(512, 1) void gemm8p(
    const ushort* __restrict__ A, const ushort* __restrict__ Bt,
    const float* __restrict__ bias, void* __restrict__ Cp, int ldc) {
    __shared__ ushort Lds[8 * 8192];   // A slots 0-3, B slots 4-7

    const int tid  = threadIdx.x;
    const int lane = tid & 63;
    const int wid  = tid >> 6;
    const int wr = wid >> 2;
    const int wc = wid & 3;
    const int fr = lane & 15;
    const int fq = lane >> 4;

    const int orig = blockIdx.x;
    const int nid  = (orig & 7) * 32 + (orig >> 3);
    const int bm = (nid >> 2) * 256;
    const int bn = (nid & 3) * 256;

    const int srow = tid >> 2;
    const int scol = ((tid & 3) ^ ((tid >> 3) & 3)) * 8;
    const size_t sA = (size_t)(bm + srow) * KD + scol;
    const size_t sB = (size_t)(bn + srow) * KD + scol;
    const int sdst = wid * 64 * 8;

    const int slotSw = (fq ^ ((fr >> 1) & 3)) * 8;
    const int aOff = (wr * 128 + fr) * 32 + slotSw;
    const int bOff = (wc * 64 + fr) * 32 + slotSw;
    const ushort* Abase = &Lds[0];
    const ushort* Bbase = &Lds[4 * 8192];

    f32x4 acc[8][4];
#pragma unroll
    for (int m = 0; m < 8; ++m)
#pragma unroll
        for (int n = 0; n < 4; ++n) acc[m][n] = (f32x4){0.f, 0.f, 0.f, 0.f};

    auto stageA = [&](int slot, int koff) {
#pragma unroll
        for (int i = 0; i < 2; ++i)
            __builtin_amdgcn_global_load_lds(
                (const __attribute__((address_space(1))) void*)(A + sA + koff + (size_t)i * 128 * KD),
                (__attribute__((address_space(3))) void*)(&Lds[slot * 8192 + i * 4096 + sdst]),
                16, 0, 0);
    };
    auto stageB = [&](int slot, int koff) {
#pragma unroll
        for (int i = 0; i < 2; ++i)
            __builtin_amdgcn_global_load_lds(
                (const __attribute__((address_space(1))) void*)(Bt + sB + koff + (size_t)i * 128 * KD),
                (__attribute__((address_space(3))) void*)(&Lds[(4 + slot) * 8192 + i * 4096 + sdst]),
                16, 0, 0);
    };

    stageA(0, 0);   stageB(0, 0);
    stageA(1, 32);  stageB(1, 32);
    stageA(2, 64);  stageB(2, 64);
    stageA(3, 96);  stageB(3, 96);
    asm volatile("s_waitcnt vmcnt(12)" ::: "memory");
    __builtin_amdgcn_sched_barrier(0);
    __builtin_amdgcn_s_barrier();
    __builtin_amdgcn_sched_barrier(0);

#pragma unroll 1
    for (int j = 0; j < 8; ++j) {
        const int e = 2 * j;

        // mp0: tile e, ksub0 | stage slot3 pair (tile e+1, k1) | vmcnt(8)
        MPHASE(0,
               { if (j >= 1) { stageA(3, (e + 1) * 64 + 32);
                               stageB(3, (e + 1) * 64 + 32); } },
               { asm volatile("s_waitcnt vmcnt(8)" ::: "memory");
                 __builtin_amdgcn_sched_barrier(0); })
        // mp1: tile e, ksub1 | stage slot0 pair (tile e+2, k0) | vmcnt(8)/(4)
        MPHASE(1,
               { if (j < 7) { stageA(0, (e + 2) * 64);
                              stageB(0, (e + 2) * 64); } },
               { if (j == 7) { asm volatile("s_waitcnt vmcnt(4)" ::: "memory"); }
                 else        { asm volatile("s_waitcnt vmcnt(8)" ::: "memory"); }
                 __builtin_amdgcn_sched_barrier(0); })
        // mp2: tile e+1, ksub0 | stage slot1 pair (tile e+2, k1) | vmcnt(8)/(0)
        MPHASE(2,
               { if (j < 7) { stageA(1, (e + 2) * 64 + 32);
                              stageB(1, (e + 2) * 64 + 32); } },
               { if (j == 7) { asm volatile("s_waitcnt vmcnt(0)" ::: "memory"); }
                 else        { asm volatile("s_waitcnt vmcnt(8)" ::: "memory"); }
                 __builtin_amdgcn_sched_barrier(0); })
        // mp3: tile e+1, ksub1 | stage slot2 pair (tile e+3, k0) | vmcnt(8)
        MPHASE(3,
               { if (j < 7) { stageA(2, (e + 3) * 64);
                              stageB(2, (e + 3) * 64); } },
               { if (j < 7) { asm volatile("s_waitcnt vmcnt(8)" ::: "memory");
                              __builtin_amdgcn_sched_barrier(0); } })
    }

    // epilogue: C/D layout col=lane&15, row=(lane>>4)*4+r
#pragma unroll
    for (int n = 0; n < 4; ++n) {
        int col = bn + wc * 64 + n * 16 + fr;
        float bv = bias[col];
#pragma unroll
        for (int m = 0; m < 8; ++m) {
#pragma unroll
            for (int r = 0; r < 4; ++r) {
                int row = bm + wr * 128 + m * 16 + fq * 4 + r;
                float v = acc[m][n][r] + bv;
                if (OUT_BF16)
                    ((ushort*)Cp)[(size_t)row * ldc + col] = f2bf(v);
                else
                    ((float*)Cp)[(size_t)row * ldc + col] = v;
            }
        }
    }
}

// ---------------------------------------------------------------------------
// Skinny GEMM for q: BM=64, BN=128(pad of 112), BK=32, 256 thr.
// ---------------------------------------------------------------------------
__global__ __launch_bounds__(256) void gemm_small(const ushort* __restrict__ A,
                                                  const ushort* __restrict__ Bt,
                                                  const float* __restrict__ bias,
                                                  float* __restrict__ Cp) {
    __shared__ ushort Als[64 * 32];
    __shared__ ushort Bls[128 * 32];
    const int tid  = threadIdx.x;
    const int lane = tid & 63;
    const int wid  = tid >> 6;
    const int wr = wid >> 1, wc = wid & 1;
    const int bm = blockIdx.y * 64;
    const int fq = lane >> 4, fr = lane & 15;

    f32x4 acc[2][4];
#pragma unroll
    for (int m = 0; m < 2; ++m)
#pragma unroll
        for (int n = 0; n < 4; ++n) acc[m][n] = (f32x4){0.f, 0.f, 0.f, 0.f};

    const int rA = tid >> 2, oA = (tid & 3) * 8;
    for (int k0 = 0; k0 < KD; k0 += 32) {
        __builtin_amdgcn_global_load_lds(
            (const __attribute__((address_space(1))) void*)&A[(size_t)(bm + rA) * KD + k0 + oA],
            (__attribute__((address_space(3))) void*)&Als[wid * 64 * 8], 16, 0, 0);
#pragma unroll
        for (int i = 0; i < 2; ++i) {
            int c = i * 256 + tid;
            __builtin_amdgcn_global_load_lds(
                (const __attribute__((address_space(1))) void*)&Bt[(size_t)(c >> 2) * KD + k0 + (c & 3) * 8],
                (__attribute__((address_space(3))) void*)&Bls[(i * 256 + wid * 64) * 8], 16, 0, 0);
        }
        __syncthreads();

        bf16x8 af[2], bfr[4];
#pragma unroll
        for (int m = 0; m < 2; ++m)
            af[m] = *(const bf16x8*)&Als[(wr * 32 + m * 16 + fr) * 32 + fq * 8];
#pragma unroll
        for (int n = 0; n < 4; ++n)
            bfr[n] = *(const bf16x8*)&Bls[(wc * 64 + n * 16 + fr) * 32 + fq * 8];
#pragma unroll
        for (int m = 0; m < 2; ++m)
#pragma unroll
            for (int n = 0; n < 4; ++n)
                acc[m][n] = __builtin_amdgcn_mfma_f32_16x16x32_bf16(
                    af[m], bfr[n], acc[m][n], 0, 0, 0);
        __syncthreads();
    }

#pragma unroll
    for (int m = 0; m < 2; ++m) {
#pragma unroll
        for (int n = 0; n < 4; ++n) {
            int col = wc * 64 + n * 16 + fr;
            if (col >= HK) continue;
            float bv = bias[col];
#pragma unroll
            for (int r = 0; r < 4; ++r) {
                int row = bm + wr * 32 + m * 16 + fq * 4 + r;
                Cp[(size_t)row * HK + col] = acc[m][n][r] + bv;
            }
        }
    }
}

// ---------------------------------------------------------------------------
// Tiled dynamic conv + fused softmax: block = (b, 16 consecutive t).
// ---------------------------------------------------------------------------
__global__ __launch_bounds__(256) void dynconv2(const ushort* __restrict__ h,
                                                const float* __restrict__ q,
                                                const float* __restrict__ cbias,
                                                ushort* __restrict__ out) {
    __shared__ ushort hw[22][1024];
    __shared__ float wsm[16][HK];
    const int tid = threadIdx.x;
    const int b  = blockIdx.x & 15;
    const int t0 = (blockIdx.x >> 4) << 4;

    for (int i = tid; i < 22 * 128; i += 256) {
        int wrow = i >> 7;
        int c8   = (i & 127) * 8;
        int tt   = t0 + wrow - PAD_LEFT;
        uint4 v = make_uint4(0, 0, 0, 0);
        if (tt >= 0 && tt < T_DIM)
            v = *(const uint4*)&h[((size_t)tt * B_DIM + b) * C_DIM + c8];
        *(uint4*)&hw[wrow][c8] = v;
    }
    {
        int tl = tid >> 4, hh = tid & 15;
        int m = (t0 + tl) * B_DIM + b;
        const float* p = &q[(size_t)m * HK + hh * K_TAPS];
        float mx = p[0];
#pragma unroll
        for (int k = 1; k < K_TAPS; ++k) mx = fmaxf(mx, p[k]);
        float e[K_TAPS], s = 0.f;
#pragma unroll
        for (int k = 0; k < K_TAPS; ++k) { e[k] = __expf(p[k] - mx); s += e[k]; }
        float inv = 1.f / s;
#pragma unroll
        for (int k = 0; k < K_TAPS; ++k) wsm[tl][hh * K_TAPS + k] = e[k] * inv;
    }
    __syncthreads();

    const int c  = tid * 4;
    const int hh = c >> 6;
    float4 bias = *(const float4*)&cbias[c];

    for (int tl = 0; tl < 16; ++tl) {
        float a0 = bias.x, a1 = bias.y, a2 = bias.z, a3 = bias.w;
#pragma unroll
        for (int k = 0; k < K_TAPS; ++k) {
            ushort4 hv = *(const ushort4*)&hw[tl + k][c];
            float wk = wsm[tl][hh * K_TAPS + k];
            a0 = fmaf(bf2f(hv.x), wk, a0);
            a1 = fmaf(bf2f(hv.y), wk, a1);
            a2 = fmaf(bf2f(hv.z), wk, a2);
            a3 = fmaf(bf2f(hv.w), wk, a3);
        }
        ushort4 o;
        o.x = f2bf(a0); o.y = f2bf(a1); o.z = f2bf(a2); o.w = f2bf(a3);
        *(ushort4*)&out[((size_t)(t0 + tl) * B_DIM + b) * C_DIM + c] = o;
    }
}

// ---------------------------------------------------------------------------
extern "C" void kernel_launch(void* const* d_in, const int* in_sizes, int n_in,
                              void* d_out, int out_size, void* d_ws,
                              size_t ws_size, hipStream_t stream) {
    const float* x     = (const float*)d_in[0];
    const float* W1    = (const float*)d_in[1];
    const float* b1    = (const float*)d_in[2];
    const float* Wq    = (const float*)d_in[3];
    const float* bq    = (const float*)d_in[4];
    const float* cbias = (const float*)d_in[5];
    const float* W2    = (const float*)d_in[6];
    const float* b2    = (const float*)d_in[7];
    float* out = (float*)d_out;

    ushort* xb    = (ushort*)d_ws;
    ushort* hb    = xb    + (size_t)M_DIM * C_DIM;
    ushort* convb = hb    + (size_t)M_DIM * C_DIM;
    ushort* W1t   = convb + (size_t)M_DIM * C_DIM;
    ushort* W2t   = W1t   + (size_t)C_DIM * C_DIM;
    ushort* Wqt   = W2t   + (size_t)C_DIM * OUT_DIM;
    float*  q     = (float*)(Wqt + (size_t)HKP * C_DIM);

    // 0) prep: x -> bf16, weights -> transposed bf16 (one launch)
    prep<<<dim3(8192 + 68 * 32), dim3(256), 0, stream>>>(
        x, xb, W1, Wq, W2, W1t, Wqt, W2t);

    // 1) h = bf16(x @ W1 + b1)
    gemm8p<true><<<dim3(256), dim3(512), 0, stream>>>(xb, W1t, b1, hb, C_DIM);

    // 2) q = h @ Wq + bq   [16384 x 112]
    gemm_small<<<dim3(1, M_DIM / 64), dim3(256), 0, stream>>>(hb, Wqt, bq, q);

    // 3+4) conv = bf16(dynconv(h, softmax(q)) + conv_bias)
    dynconv2<<<dim3(B_DIM * T_DIM / 16), dim3(256), 0, stream>>>(
        hb, q, cbias, convb);

    // 5) out = conv @ W2 + b2
    gemm8p<false><<<dim3(256), dim3(512), 0, stream>>>(convb, W2t, b2, out,
                                                       OUT_DIM);
}